// Round 1
// baseline (281.660 us; speedup 1.0000x reference)
//
#include <hip/hip_runtime.h>
#include <cmath>

// PSNR + 3D-SSIM, pred/gt (N=4, C=16->D, H=512, W=512) f32.
// R9: dot2-based blurs. Staged fields are packed as f16 TAP-AXIS pairs
// (row-pairs for the vertical H-blur, column-pairs for the W-blur) so each
// 11-tap blur is 6x v_dot2_f32_f16 per channel instead of 11 unpack + 11 fma.
// Even/odd tap phase handled by two zero-padded f16 coeff tables (ge/go),
// selected per-thread by parity (no divergence). D-blur weights (clamp-folded
// 16x16, transposed) live in kernarg -> SGPR s_loads, no LDS broadcast reads.
// f16 storage (10-bit mantissa) is strictly more accurate than R8's bf16.

#define NB 4
#define DD 16
#define HH 512
#define WW 512
#define SLICE (HH * WW)
#define VOL (DD * SLICE)
#define C1F 0.0001f
#define C2F 0.0009f

#define TH 16          // tile rows
#define TW 32          // tile cols
#define SW 42          // staged cols (TW+10)
#define RP 13          // staged row-pairs ((TH+10)/2)
#define CP 21          // col-pairs in staged width
#define CPP 22         // padded plane stride (uint2 elements)
#define CPT 22         // tmp row stride (uint2 elements)
#define NTHR 512
#define SIT (RP * SW)  // 546 stage items
#define HIT (TH * CP)  // 336 H-blur items
#define XTRA (SIT - NTHR)  // 34 second-slot stage items

typedef _Float16 h2v __attribute__((ext_vector_type(2)));

struct KArg {
  float wlT[DD * DD];      // wlT[d*16+dout] = clamp-folded D-blur weight
  unsigned ge[6], go[6];   // f16x2 tap-pair coeffs, even/odd phase
};

__device__ inline float dot2h(unsigned a, unsigned b, float c) {
#if __has_builtin(__builtin_amdgcn_fdot2)
  return __builtin_amdgcn_fdot2(__builtin_bit_cast(h2v, a),
                                __builtin_bit_cast(h2v, b), c, false);
#else
  h2v av = __builtin_bit_cast(h2v, a), bv = __builtin_bit_cast(h2v, b);
  return fmaf((float)av.y, (float)bv.y, fmaf((float)av.x, (float)bv.x, c));
#endif
}
__device__ inline unsigned pkh(float a, float b) {
  return __builtin_bit_cast(unsigned, __builtin_amdgcn_cvt_pkrtz(a, b));
}
__device__ inline int iclamp(int v, int lo, int hi) {
  return v < lo ? lo : (v > hi ? hi : v);
}

__device__ inline float block_sum512(float v) {
#pragma unroll
  for (int o = 32; o > 0; o >>= 1) v += __shfl_down(v, o, 64);
  __shared__ float r[8];
  if ((threadIdx.x & 63) == 0) r[threadIdx.x >> 6] = v;
  __syncthreads();
  float out = 0.f;
  if (threadIdx.x == 0) {
#pragma unroll
    for (int i = 0; i < 8; ++i) out += r[i];
  }
  __syncthreads();
  return out;
}

__global__ void zero_acc_k(float* acc) {
  if (threadIdx.x < 8) acc[threadIdx.x] = 0.f;
}

__global__ __launch_bounds__(NTHR, 2) void fused_k(
    const float* __restrict__ pred, const float* __restrict__ gt,
    float* __restrict__ acc, KArg ka) {
  // staged slice, double-buffered. Word = f16x2 row-pair of ONE channel.
  // layout: [(rp*2 + colparity)*CPP + colpair]
  __shared__ uint2 sA[2][RP * 2 * CPP];  // {.x = S-pair, .y = D-pair}
  __shared__ uint2 sB[2][RP * 2 * CPP];  // {.x = S2-pair, .y = D2-pair}
  __shared__ uint2 tA[TH * CPT];         // H-blurred, col-pair packed {S,D}
  __shared__ uint2 tB[TH * CPT];         // {S2,D2}

  int b = blockIdx.x;
  int tile = b & 511;                // 32 h-tiles x 16 w-tiles
  int n = b >> 9;
  int th0 = (tile >> 4) * TH;
  int tw0 = (tile & 15) * TW;
  int t = threadIdx.x;

  // ---- stage metadata, slot 0 (item i = t, always valid since NTHR<SIT)
  int rpA = t / SW, xA = t - rpA * SW;
  int r0A = th0 + 2 * rpA - 5;
  int gxA = iclamp(tw0 + xA - 5, 0, WW - 1);
  int go00 = iclamp(r0A, 0, HH - 1) * WW + gxA;
  int go01 = iclamp(r0A + 1, 0, HH - 1) * WW + gxA;
  int wof0 = (rpA * 2 + (xA & 1)) * CPP + (xA >> 1);
  bool oxA = (xA >= 5) && (xA < 5 + TW);
  float o00 = (oxA && rpA >= 3 && rpA <= 10) ? 1.f : 0.f;  // row 2rp owned
  float o01 = (oxA && rpA >= 2 && rpA <= 9) ? 1.f : 0.f;   // row 2rp+1 owned

  // ---- stage metadata, slot 1 (items 512..545 -> threads 478..511)
  int i1 = t + XTRA;                 // always in [34, 546): safe to index
  bool has2 = (i1 >= NTHR);
  int rpB = i1 / SW, xB = i1 - rpB * SW;
  int r0B = th0 + 2 * rpB - 5;
  int gxB = iclamp(tw0 + xB - 5, 0, WW - 1);
  int go10 = iclamp(r0B, 0, HH - 1) * WW + gxB;
  int go11 = iclamp(r0B + 1, 0, HH - 1) * WW + gxB;
  int wof1 = (rpB * 2 + (xB & 1)) * CPP + (xB >> 1);
  bool oxB = (xB >= 5) && (xB < 5 + TW);
  float o10 = (oxB && rpB >= 3 && rpB <= 10) ? 1.f : 0.f;
  float o11 = (oxB && rpB >= 2 && rpB <= 9) ? 1.f : 0.f;

  // ---- H-blur metadata (items: r in [0,16), cp in [0,21))
  bool hasH = (t < HIT);
  int hr = t / CP, hcp = t - hr * CP;
  int hbase = (hr >> 1) * (2 * CPP) + hcp;  // plane0 addr of first row-pair
  int htad = hr * CPT + hcp;

  // ---- W-blur metadata (one owned px per thread)
  int wy = t >> 5, wx = t & 31;
  int wbase = wy * CPT + (wx >> 1);

  // parity-selected f16x2 coeff tables (hoisted; fixed per thread)
  unsigned ch[6], cw[6];
#pragma unroll
  for (int j = 0; j < 6; ++j) {
    ch[j] = (hr & 1) ? ka.go[j] : ka.ge[j];
    cw[j] = (wx & 1) ? ka.go[j] : ka.ge[j];
  }

  const float* pb = pred + (size_t)n * VOL;
  const float* qb = gt + (size_t)n * VOL;

  // prefetch slice 0
  float p00 = pb[go00], q00 = qb[go00], p01 = pb[go01], q01 = qb[go01];
  float p10 = 0.f, q10 = 0.f, p11 = 0.f, q11 = 0.f;
  if (has2) { p10 = pb[go10]; q10 = qb[go10]; p11 = pb[go11]; q11 = qb[go11]; }

  float psnr = 0.f;
  float a0[DD], a1[DD], a2[DD], a3[DD];
#pragma unroll
  for (int j = 0; j < DD; ++j) { a0[j] = a1[j] = a2[j] = a3[j] = 0.f; }

#pragma unroll 1
  for (int d = 0; d < DD; ++d) {
    uint2* sAb = sA[d & 1];
    uint2* sBb = sB[d & 1];
    // ---- stage slice d from prefetched regs (f16 row-pair packed)
    {
      float S0 = p00 + q00, D0 = p00 - q00;
      float S1 = p01 + q01, D1 = p01 - q01;
      float dd0 = D0 * D0, dd1 = D1 * D1;
      psnr = fmaf(o00, dd0, psnr);
      psnr = fmaf(o01, dd1, psnr);
      sAb[wof0] = make_uint2(pkh(S0, S1), pkh(D0, D1));
      sBb[wof0] = make_uint2(pkh(S0 * S0, S1 * S1), pkh(dd0, dd1));
    }
    if (has2) {
      float S0 = p10 + q10, D0 = p10 - q10;
      float S1 = p11 + q11, D1 = p11 - q11;
      float dd0 = D0 * D0, dd1 = D1 * D1;
      psnr = fmaf(o10, dd0, psnr);
      psnr = fmaf(o11, dd1, psnr);
      sAb[wof1] = make_uint2(pkh(S0, S1), pkh(D0, D1));
      sBb[wof1] = make_uint2(pkh(S0 * S0, S1 * S1), pkh(dd0, dd1));
    }
    __syncthreads();   // sd[buf] ready; also fences tmp (W-reads of d-1 done)

    // prefetch slice d+1
    if (d < DD - 1) {
      const float* pd = pb + (size_t)(d + 1) * SLICE;
      const float* qd = qb + (size_t)(d + 1) * SLICE;
      p00 = pd[go00]; q00 = qd[go00]; p01 = pd[go01]; q01 = qd[go01];
      if (has2) { p10 = pd[go10]; q10 = qd[go10]; p11 = pd[go11]; q11 = qd[go11]; }
    }

    // ---- H-blur (vertical): item = (row r, col-pair cp), both parities
    if (hasH) {
      float e0 = 0.f, e1 = 0.f, e2 = 0.f, e3 = 0.f;
      float f0 = 0.f, f1 = 0.f, f2 = 0.f, f3 = 0.f;
#pragma unroll
      for (int j = 0; j < 6; ++j) {
        uint2 va0 = sAb[hbase + j * (2 * CPP)];        // col 2cp
        uint2 va1 = sAb[hbase + j * (2 * CPP) + CPP];  // col 2cp+1
        uint2 vb0 = sBb[hbase + j * (2 * CPP)];
        uint2 vb1 = sBb[hbase + j * (2 * CPP) + CPP];
        unsigned c = ch[j];
        e0 = dot2h(c, va0.x, e0); e1 = dot2h(c, va0.y, e1);
        f0 = dot2h(c, va1.x, f0); f1 = dot2h(c, va1.y, f1);
        e2 = dot2h(c, vb0.x, e2); e3 = dot2h(c, vb0.y, e3);
        f2 = dot2h(c, vb1.x, f2); f3 = dot2h(c, vb1.y, f3);
      }
      // repack as col-pairs for the W-blur
      tA[htad] = make_uint2(pkh(e0, f0), pkh(e1, f1));
      tB[htad] = make_uint2(pkh(e2, f2), pkh(e3, f3));
    }
    __syncthreads();

    // ---- W-blur at (wy, wx): 6 dot2 per channel over col-pairs
    float w0 = 0.f, w1 = 0.f, w2 = 0.f, w3 = 0.f;
#pragma unroll
    for (int j = 0; j < 6; ++j) {
      uint2 va = tA[wbase + j];
      uint2 vb = tB[wbase + j];
      unsigned c = cw[j];
      w0 = dot2h(c, va.x, w0);
      w1 = dot2h(c, va.y, w1);
      w2 = dot2h(c, vb.x, w2);
      w3 = dot2h(c, vb.y, w3);
    }
    // ---- D-blur accumulate; weights from kernarg (uniform -> s_load + fma)
    const float* wl = ka.wlT + d * DD;
#pragma unroll
    for (int dout = 0; dout < DD; ++dout) {
      float w = wl[dout];
      a0[dout] = fmaf(w, w0, a0[dout]);
      a1[dout] = fmaf(w, w1, a1[dout]);
      a2[dout] = fmaf(w, w2, a2[dout]);
      a3[dout] = fmaf(w, w3, a3[dout]);
    }
    // no trailing barrier: next stage writes the other sd buffer; the next
    // post-stage __syncthreads fences tmp before H overwrites it.
  }

  // SSIM over the 16 douts of this px
  float ssum = 0.f;
#pragma unroll
  for (int j = 0; j < DD; ++j) {
    float Sb = a0[j], Db = a1[j], B1 = a2[j], B2 = a3[j];
    float SS = Sb * Sb, DDm = Db * Db;
    float m12_2 = (SS - DDm) * 0.5f;     // 2*mu1*mu2
    float msq   = (SS + DDm) * 0.5f;     // mu1^2 + mu2^2
    float Epq   = (B1 - B2) * 0.25f;     // E[pq]
    float Esum  = (B1 + B2) * 0.5f;      // E[p^2+q^2]
    float sig12_2 = 2.f * Epq - m12_2;   // 2*sigma12
    float svar    = Esum - msq;          // sigma1^2 + sigma2^2
    float num = (m12_2 + C1F) * (sig12_2 + C2F);
    float den = (msq + C1F) * (svar + C2F);
    ssum += num / den;
  }
  float bs = block_sum512(ssum);
  if (t == 0) atomicAdd(&acc[4 + n], bs);
  float bp = block_sum512(psnr);
  if (t == 0) atomicAdd(&acc[n], bp);
}

__global__ void final_k(const float* __restrict__ acc, float* __restrict__ out) {
  if (threadIdx.x == 0 && blockIdx.x == 0) {
    double psnr = 0.0, ssim = 0.0;
    for (int n = 0; n < NB; ++n) {
      double mse = (double)acc[n] / (double)VOL;
      psnr += 10.0 * log10(1.0 / mse);
      ssim += (double)acc[4 + n] / (double)VOL;
    }
    out[0] = (float)psnr;
    out[1] = (float)ssim;
    out[2] = (float)NB;
  }
}

// host f32 -> f16 (round-to-nearest-even)
static unsigned short f2h(float f) {
  union { float f; unsigned u; } v; v.f = f;
  unsigned u = v.u;
  unsigned s = (u >> 16) & 0x8000u;
  int e = (int)((u >> 23) & 0xff) - 127 + 15;
  unsigned m = u & 0x7fffffu;
  if (e <= 0) return (unsigned short)s;          // flush (never hit: min g ~1e-3)
  if (e >= 31) return (unsigned short)(s | 0x7c00u);
  unsigned h = ((unsigned)e << 10) | (m >> 13);
  unsigned rem = m & 0x1fffu;
  if (rem > 0x1000u || (rem == 0x1000u && (h & 1u))) h++;
  return (unsigned short)(s | h);
}

extern "C" void kernel_launch(void* const* d_in, const int* in_sizes, int n_in,
                              void* d_out, int out_size, void* d_ws, size_t ws_size,
                              hipStream_t stream) {
  const float* pred = (const float*)d_in[0];
  const float* gt = (const float*)d_in[1];
  float* acc = (float*)d_ws;    // 8 floats

  double tt[11], s = 0.0;
  for (int i = 0; i < 11; ++i) {
    double x = i - 5;
    tt[i] = exp(-(x * x) / 4.5);
    s += tt[i];
  }
  float g[11];
  for (int i = 0; i < 11; ++i) g[i] = (float)(tt[i] / s);

  KArg ka;
  // clamp-folded D-blur weight matrix, transposed: wlT[d][dout]
  for (int dout = 0; dout < DD; ++dout) {
    for (int d = 0; d < DD; ++d) {
      float w = 0.f;
      for (int k = 0; k < 11; ++k) {
        int j = dout + k - 5;
        j = j < 0 ? 0 : (j > 15 ? 15 : j);
        if (j == d) w += g[k];
      }
      ka.wlT[d * DD + dout] = w;
    }
  }
  // even-phase pairs: (g0,g1)(g2,g3)(g4,g5)(g6,g7)(g8,g9)(g10,0)
  for (int j = 0; j < 5; ++j)
    ka.ge[j] = (unsigned)f2h(g[2 * j]) | ((unsigned)f2h(g[2 * j + 1]) << 16);
  ka.ge[5] = (unsigned)f2h(g[10]);
  // odd-phase pairs: (0,g0)(g1,g2)(g3,g4)(g5,g6)(g7,g8)(g9,g10)
  ka.go[0] = ((unsigned)f2h(g[0])) << 16;
  for (int j = 1; j < 6; ++j)
    ka.go[j] = (unsigned)f2h(g[2 * j - 1]) | ((unsigned)f2h(g[2 * j]) << 16);

  zero_acc_k<<<1, 64, 0, stream>>>(acc);
  fused_k<<<NB * 512, NTHR, 0, stream>>>(pred, gt, acc, ka);
  final_k<<<1, 1, 0, stream>>>(acc, (float*)d_out);
}